// Round 9
// baseline (263.874 us; speedup 1.0000x reference)
//
#include <hip/hip_runtime.h>

// ---------------------------------------------------------------------------
// MHA: out = softmax_causal((xWq)(xWk)^T / sqrt(64)) (xWv) Wo
// B=4 T=2048 D=1024 H=16 Dh=64.  All matmuls in bf16 MFMA (fp32 accum).
// Attention transposed (S^T = K Q^T, O^T = V^T P^T), unnormalized softmax
// p = exp2(s), l via MFMA against a ones-row appended to V^T.
// R9: latency-bound fix -> 512-thr blocks, each wave owns strip A (tile p)
// + strip B (tile 15-p) in ONE k-loop; B always active (no R6-style wave
// idling), A reuses B's kf/vf frags while live.  16 waves/CU.
// ---------------------------------------------------------------------------

typedef short  short8  __attribute__((ext_vector_type(8)));
typedef short  short4v __attribute__((ext_vector_type(4)));
typedef float  floatx4 __attribute__((ext_vector_type(4)));
typedef unsigned uint2v __attribute__((ext_vector_type(2)));

#define T_SZ 2048
#define DM   1024

// 0.125 (Dh^-0.5) * log2(e): softmax in base-2 domain -> native v_exp_f32
#define QSCALE 0.18033688011112042f

__device__ __forceinline__ short f2bf(float f) {
  unsigned u = __float_as_uint(f);
  u += 0x7fffu + ((u >> 16) & 1u);        // RNE
  return (short)(u >> 16);
}

#if defined(__has_builtin) && __has_builtin(__builtin_amdgcn_cvt_pk_bf16_f32)
typedef __bf16 bf16x2_t __attribute__((ext_vector_type(2)));
__device__ __forceinline__ unsigned pack_bf(float lo, float hi) {   // 1 VALU op
  return __builtin_bit_cast(unsigned, __builtin_amdgcn_cvt_pk_bf16_f32(lo, hi));
}
#else
__device__ __forceinline__ unsigned pack_bf(float lo, float hi) {   // 3 VALU ops
  return __builtin_amdgcn_perm(__float_as_uint(hi) + 0x8000u,
                               __float_as_uint(lo) + 0x8000u, 0x07060302u);
}
#endif

#if defined(__has_builtin) && __has_builtin(__builtin_amdgcn_exp2f)
__device__ __forceinline__ float fexp2(float x) { return __builtin_amdgcn_exp2f(x); }
#else
__device__ __forceinline__ float fexp2(float x) { return exp2f(x); }
#endif

__device__ __forceinline__ void gll16(const void* g, void* l) {
  __builtin_amdgcn_global_load_lds((const __attribute__((address_space(1))) void*)g,
                                   (__attribute__((address_space(3))) void*)l, 16, 0, 0);
}

// -------------------------------------------------- converts, one launch
// z in [0,4): W[z] fp32 [K,N] -> bf16 W^T [N,K]   (grid x,y = 32,32; block 32x8)
// z == 4   : x fp32 -> bf16 flat
__global__ void cvt_kernel(const float* __restrict__ s0, const float* __restrict__ s1,
                           const float* __restrict__ s2, const float* __restrict__ s3,
                           short* __restrict__ dst,
                           const float* __restrict__ x, short* __restrict__ xb) {
  const int tx = threadIdx.x, ty = threadIdx.y;       // block (32,8)
  if (blockIdx.z == 4) {                              // ---- x -> bf16
    const int tid = ty * 32 + tx;
    const int blk = blockIdx.y * 32 + blockIdx.x;     // 0..1023
    int i = (blk * 256 + tid) * 4;
#pragma unroll
    for (int j = 0; j < 8; ++j) {
      const float4 v = *(const float4*)(x + i);
      short4v o;
      o.x = f2bf(v.x); o.y = f2bf(v.y); o.z = f2bf(v.z); o.w = f2bf(v.w);
      *(short4v*)(xb + i) = o;
      i += 1048576;
    }
    return;
  }
  const float* srcs[4] = {s0, s1, s2, s3};
  const float* src = srcs[blockIdx.z];
  short* d = dst + (size_t)blockIdx.z * 1048576;
  __shared__ float tile[32][33];
  const int n_base = blockIdx.x * 32, k_base = blockIdx.y * 32;
#pragma unroll
  for (int j = 0; j < 4; ++j)
    tile[ty + j * 8][tx] = src[(size_t)(k_base + ty + j * 8) * 1024 + n_base + tx];
  __syncthreads();
#pragma unroll
  for (int j = 0; j < 4; ++j)
    d[(size_t)(n_base + ty + j * 8) * 1024 + k_base + tx] = f2bf(tile[tx][ty + j * 8]);
}

// -------------------------------------------------- GEMM  C = A[M,K] * Bt[N,K]^T
// XCD-swizzled block mapping: lid%8 = XCD; each XCD owns 8 m-stripes.
// MODE 0: QKV epilogue.  Q (wsel0, scaled) / K (wsel1) -> bf16 [bh][t][64];
//         V (wsel2) -> V^T bf16 [bh][64][t] (transpose fused, 8B packed stores)
// MODE 1: fp32 row-major epilogue -> d_out
template <int MODE>
__global__ void gemm_bt(const short* __restrict__ A, const short* __restrict__ Bt,
                        short* __restrict__ obf, short* __restrict__ vt,
                        float* __restrict__ of, int K) {
  __shared__ short As[128 * 32];
  __shared__ short Bs[128 * 32];
  const int tid  = threadIdx.x;
  const int w    = tid >> 6, lane = tid & 63;
  const int quad = lane >> 4, l15 = lane & 15;
  const int wr   = w >> 1, wc = w & 1;
  const int lid  = (int)blockIdx.y * 64 + (int)blockIdx.x;
  const int m0   = (((lid & 7) + 8 * ((lid >> 3) & 7))) * 128;
  const int n0   = (lid >> 6) * 128;
  const int arow = tid >> 2, apart = tid & 3;

  floatx4 acc[4][4] = {};

  for (int kk = 0; kk < K; kk += 32) {
    gll16(A  + (size_t)(m0 + arow) * K      + kk + apart * 8, &As[tid * 8]);
    gll16(A  + (size_t)(m0 + 64 + arow) * K + kk + apart * 8, &As[(256 + tid) * 8]);
    gll16(Bt + (size_t)(n0 + arow) * K      + kk + apart * 8, &Bs[tid * 8]);
    gll16(Bt + (size_t)(n0 + 64 + arow) * K + kk + apart * 8, &Bs[(256 + tid) * 8]);
    __syncthreads();
    short8 af[4], bf[4];
#pragma unroll
    for (int i = 0; i < 4; ++i)
      af[i] = *(const short8*)&As[(wr * 64 + i * 16 + l15) * 32 + quad * 8];
#pragma unroll
    for (int j = 0; j < 4; ++j)
      bf[j] = *(const short8*)&Bs[(wc * 64 + j * 16 + l15) * 32 + quad * 8];
#pragma unroll
    for (int i = 0; i < 4; ++i)
#pragma unroll
      for (int j = 0; j < 4; ++j)
        acc[i][j] = __builtin_amdgcn_mfma_f32_16x16x32_bf16(af[i], bf[j], acc[i][j], 0, 0, 0);
    __syncthreads();
  }

  if (MODE == 0) {
    const int wsel = n0 >> 10;
    const int ncol0 = (n0 & 1023) + wc * 64;
    if (wsel < 2) {
      const float scale = (wsel == 0) ? QSCALE : 1.0f;
      short* outw = obf + (size_t)wsel * (64u * 2048u * 64u);
#pragma unroll
      for (int i = 0; i < 4; ++i) {
        const int row0 = m0 + wr * 64 + i * 16 + quad * 4;
#pragma unroll
        for (int j = 0; j < 4; ++j) {
          const int col = ncol0 + j * 16 + l15;
          const int h = col >> 6, d = col & 63;
#pragma unroll
          for (int r = 0; r < 4; ++r) {
            const int rg = row0 + r;
            const int b = rg >> 11, t = rg & 2047;
            outw[(((size_t)(b * 16 + h) * 2048 + t) << 6) + d] = f2bf(acc[i][j][r] * scale);
          }
        }
      }
    } else {                         // V -> V^T [bh][d][2048], 4 consecutive t per lane
#pragma unroll
      for (int i = 0; i < 4; ++i) {
        const int row0 = m0 + wr * 64 + i * 16 + quad * 4;   // t base (mult of 4)
        const int b = row0 >> 11, t = row0 & 2047;
#pragma unroll
        for (int j = 0; j < 4; ++j) {
          const int col = ncol0 + j * 16 + l15;
          const int h = col >> 6, d = col & 63;
          short4v pv;
#pragma unroll
          for (int r = 0; r < 4; ++r) pv[r] = f2bf(acc[i][j][r]);
          *(short4v*)(vt + (((size_t)(b * 16 + h) * 64 + d) << 11) + t) = pv;
        }
      }
    }
  } else {
#pragma unroll
    for (int i = 0; i < 4; ++i) {
      const int row0 = m0 + wr * 64 + i * 16 + quad * 4;
#pragma unroll
      for (int j = 0; j < 4; ++j) {
        const int col = n0 + wc * 64 + j * 16 + l15;
#pragma unroll
        for (int r = 0; r < 4; ++r)
          of[(size_t)(row0 + r) * 1024 + col] = acc[i][j][r];
      }
    }
  }
}

// -------------------------------------------------- flash attention (causal, transposed)
// grid (8, 64), block 512 (8 waves).  bh = bx + 8*(by&7) -> one XCD per bh
// group.  g = by>>3 -> p = g<4 ? g : 11-g (co-resident block pairs sum to
// constant work).  ONE k-loop over kmax = 16-p tiles; wave w owns strip A
// (16 q of tile p, active kt<=p) + strip B (16 q of tile 15-p, always
// active).  kf/vf frag reads serve both strips while A lives.  One lane per
// q.  Half-width per-wave P buffer (mt 0-3 -> chunks 0-1, mt 4-7 -> 2-3).
// l = softmax denominator via MFMA against ones-row 64 of Vs.
__global__ __launch_bounds__(512, 4) void attn_kernel(
    const short* __restrict__ Qg, const short* __restrict__ Kg,
    const short* __restrict__ Vt, short* __restrict__ ctx) {
  __shared__ short Ks[128 * 72];       // [t_k][d]                     18.00 KB
  __shared__ short Vs[80 * 132];       // [d][t_k], row 64 = ones      20.63 KB
  __shared__ short Ps[8 * 32 * 68];    // per-wave [q(32)][t_k half]   34.00 KB

  const int tid  = threadIdx.x;
  const int w    = tid >> 6, lane = tid & 63;
  const int quad = lane >> 4, l15 = lane & 15;
  const int bh = (int)blockIdx.x + 8 * ((int)blockIdx.y & 7);
  const int g  = (int)blockIdx.y >> 3;
  const int p  = (g < 4) ? g : 11 - g;          // pair (p, 15-p), p in [0,8)
  const int b  = bh >> 4, h = bh & 15;

  const size_t base = (size_t)bh * (T_SZ * 64);
  const short* Qb  = Qg + base;
  const short* Kb  = Kg + base;
  const short* Vtb = Vt + base;
  short* Pw = &Ps[w * (32 * 68)];

  // staging (512 thr): K row skr cols [skc,skc+16); V row svr cols [svc,svc+16)
  const int skr = tid >> 2, skc = (tid & 3) * 16;
  const int svr = tid >> 3, svc = (tid & 7) * 16;

  // ones-row 64 of Vs (l-reduction); spill into row 65 harmless
  if (tid < 17) {
    short8 one;
#pragma unroll
    for (int j = 0; j < 8; ++j) one[j] = (short)0x3F80;
    *(short8*)&Vs[64 * 132 + tid * 8] = one;
  }

  const int rowA = (p << 7) + w * 16;           // strip A: tile p
  const int rowB = ((15 - p) << 7) + w * 16;    // strip B: tile 15-p

  const short8 qA0 = *(const short8*)(Qb + (size_t)(rowA + l15) * 64 + quad * 8);
  const short8 qA1 = *(const short8*)(Qb + (size_t)(rowA + l15) * 64 + 32 + quad * 8);
  const short8 qB0 = *(const short8*)(Qb + (size_t)(rowB + l15) * 64 + quad * 8);
  const short8 qB1 = *(const short8*)(Qb + (size_t)(rowB + l15) * 64 + 32 + quad * 8);

  floatx4 OA[4] = {}, OB[4] = {};
  floatx4 O5A = {}, O5B = {};                   // l lands in C row 0 (quad0/reg0)

  const int kmax = 16 - p;
  // preload tile 0
  short8 kR0 = *(const short8*)(Kb + (size_t)skr * 64 + skc);
  short8 kR1 = *(const short8*)(Kb + (size_t)skr * 64 + skc + 8);
  short8 vR0 = *(const short8*)(Vtb + (size_t)svr * 2048 + svc);
  short8 vR1 = *(const short8*)(Vtb + (size_t)svr * 2048 + svc + 8);

  for (int kt = 0; kt < kmax; ++kt) {
    const int k0 = kt << 7;
    __syncthreads();                            // prior tile's LDS reads done
    *(short8*)&Ks[skr * 72 + skc] = kR0;
    *(short8*)&Ks[skr * 72 + skc + 8] = kR1;
    *(short8*)&Vs[svr * 132 + svc] = vR0;
    *(short8*)&Vs[svr * 132 + svc + 8] = vR1;
    if (kt + 1 < kmax) {                        // prefetch next tile
      const int kn = (kt + 1) << 7;
      kR0 = *(const short8*)(Kb + (size_t)(kn + skr) * 64 + skc);
      kR1 = *(const short8*)(Kb + (size_t)(kn + skr) * 64 + skc + 8);
      vR0 = *(const short8*)(Vtb + (size_t)svr * 2048 + kn + svc);
      vR1 = *(const short8*)(Vtb + (size_t)svr * 2048 + kn + svc + 8);
    }
    __syncthreads();                            // staged LDS visible

    const bool aA = (kt <= p);                  // strip A alive this tile
    const int dkA = rowA - k0;                  // valid when aA (>= 0)
    const int dkB = rowB - k0;                  // always >= 0
    const int limA = dkA + l15, limB = dkB + l15;

#pragma unroll
    for (int half = 0; half < 2; ++half) {
      if (half * 64 > dkB) break;               // no active chunk in this half
      // ---- P for m-tiles [4*half, 4*half+4) into half-width buffer
#pragma unroll
      for (int mt2 = 0; mt2 < 4; ++mt2) {
        const int mt = half * 4 + mt2;
        const int pa = l15 * 68 + mt2 * 16 + quad * 4;
        const int pb = (16 + l15) * 68 + mt2 * 16 + quad * 4;
        if (mt * 16 <= dkB) {
          const short8 kf0 = *(const short8*)&Ks[(mt * 16 + l15) * 72 + quad * 8];
          const short8 kf1 = *(const short8*)&Ks[(mt * 16 + l15) * 72 + 32 + quad * 8];
          {                                     // ---- strip B
            floatx4 s = {};
            s = __builtin_amdgcn_mfma_f32_16x16x32_bf16(kf0, qB0, s, 0, 0, 0);
            s = __builtin_amdgcn_mfma_f32_16x16x32_bf16(kf1, qB1, s, 0, 0, 0);
            if (mt * 16 + 15 > dkB) {
#pragma unroll
              for (int r = 0; r < 4; ++r)
                if (mt * 16 + quad * 4 + r > limB) s[r] = -1e30f;
            }
            floatx4 e;
#pragma unroll
            for (int r = 0; r < 4; ++r) e[r] = fexp2(s[r]);
            uint2v pd;
            pd.x = pack_bf(e[0], e[1]);
            pd.y = pack_bf(e[2], e[3]);
            *(uint2v*)&Pw[pb] = pd;
          }
          if (aA && mt * 16 <= dkA) {           // ---- strip A (reuses kf)
            floatx4 s = {};
            s = __builtin_amdgcn_mfma_f32_16x16x32_bf16(kf0, qA0, s, 0, 0, 0);
            s = __builtin_amdgcn_mfma_f32_16x16x32_bf16(kf1, qA1, s, 0, 0, 0);
            if (mt * 16 + 15 > dkA) {
#pragma unroll
              for (int r = 0; r < 4; ++r)
                if (mt * 16 + quad * 4 + r > limA) s[r] = -1e30f;
            }
            floatx4 e;
#pragma unroll
            for (int r = 0; r < 4; ++r) e[r] = fexp2(s[r]);
            uint2v pd;
            pd.x = pack_bf(e[0], e[1]);
            pd.y = pack_bf(e[2], e[3]);
            *(uint2v*)&Pw[pa] = pd;
          } else if (aA && (mt >> 1) * 32 <= dkA) {   // zero chunk-partner (A)
            uint2v z; z.x = 0; z.y = 0;
            *(uint2v*)&Pw[pa] = z;
          }
        } else {
          uint2v z; z.x = 0; z.y = 0;
          if ((mt >> 1) * 32 <= dkB) *(uint2v*)&Pw[pb] = z;
          if (aA && (mt >> 1) * 32 <= dkA) *(uint2v*)&Pw[pa] = z;
        }
      }
      // ---- PV for this half's chunks
#pragma unroll
      for (int cc = 0; cc < 2; ++cc) {
        const int c = half * 2 + cc;
        if (c * 32 <= dkB) {
          const short8 vfl = *(const short8*)&Vs[(64 + l15) * 132 + c * 32 + quad * 8];
          short8 vf[4];
#pragma unroll
          for (int dt = 0; dt < 4; ++dt)
            vf[dt] = *(const short8*)&Vs[(dt * 16 + l15) * 132 + c * 32 + quad * 8];
          const short8 pfB = *(const short8*)&Pw[(16 + l15) * 68 + cc * 32 + quad * 8];
#pragma unroll
          for (int dt = 0; dt < 4; ++dt)
            OB[dt] = __builtin_amdgcn_mfma_f32_16x16x32_bf16(vf[dt], pfB, OB[dt], 0, 0, 0);
          O5B = __builtin_amdgcn_mfma_f32_16x16x32_bf16(vfl, pfB, O5B, 0, 0, 0);
          if (aA && c * 32 <= dkA) {            // reuses vf/vfl
            const short8 pfA = *(const short8*)&Pw[l15 * 68 + cc * 32 + quad * 8];
#pragma unroll
            for (int dt = 0; dt < 4; ++dt)
              OA[dt] = __builtin_amdgcn_mfma_f32_16x16x32_bf16(vf[dt], pfA, OA[dt], 0, 0, 0);
            O5A = __builtin_amdgcn_mfma_f32_16x16x32_bf16(vfl, pfA, O5A, 0, 0, 0);
          }
        }
      }
    }
  }

  // epilogue: l = O5[0] broadcast from quad0 lane l15 (C row 0 = ones-row)
  {
    const float invA = 1.0f / __shfl(O5A[0], l15);
    const int t = rowA + l15;
    short* cb = ctx + (((size_t)(b * T_SZ + t)) << 10) + h * 64 + quad * 4;
#pragma unroll
    for (int dt = 0; dt < 4; ++dt) {
      short4v o4;
#pragma unroll
      for (int r = 0; r < 4; ++r) o4[r] = f2bf(OA[dt][r] * invA);
      *(short4v*)(cb + dt * 16) = o4;
    }
  }
  {
    const float invB = 1.0f / __shfl(O5B[0], l15);
    const int t = rowB + l15;
    short* cb = ctx + (((size_t)(b * T_SZ + t)) << 10) + h * 64 + quad * 4;
#pragma unroll
    for (int dt = 0; dt < 4; ++dt) {
      short4v o4;
#pragma unroll
      for (int r = 0; r < 4; ++r) o4[r] = f2bf(OB[dt][r] * invB);
      *(short4v*)(cb + dt * 16) = o4;
    }
  }
}

// --------------------------------------------------
extern "C" void kernel_launch(void* const* d_in, const int* in_sizes, int n_in,
                              void* d_out, int out_size, void* d_ws, size_t ws_size,
                              hipStream_t stream) {
  const float* x  = (const float*)d_in[0];
  const float* Wq = (const float*)d_in[1];
  const float* Wk = (const float*)d_in[2];
  const float* Wv = (const float*)d_in[3];
  const float* Wo = (const float*)d_in[4];
  float* out = (float*)d_out;

  // bf16 workspace (72 MB):
  //   xb [8M]  : x bf16; dead after gemm<0> -> reused as ctx
  //   Wt [4x1M]: transposed weights
  //   Qb,Kb [8M each] : projections [bh][t][64]
  //   Vt [8M]  : V^T [bh][64][t]  (written directly by gemm<0> epilogue)
  short* ws  = (short*)d_ws;
  short* xb  = ws;
  short* Wt  = ws + 8388608;
  short* Qb  = Wt + 4 * 1048576;
  short* Kb  = Qb + 8388608;
  short* Vt  = Kb + 8388608;
  short* ctx = xb;

  cvt_kernel<<<dim3(32, 32, 5), dim3(32, 8), 0, stream>>>(Wq, Wk, Wv, Wo, Wt, x, xb);
  gemm_bt<0><<<dim3(64, 24), 256, 0, stream>>>(xb, Wt, Qb, Vt, nullptr, 1024);
  attn_kernel<<<dim3(8, 64), 512, 0, stream>>>(Qb, Kb, Vt, ctx);
  gemm_bt<1><<<dim3(64, 8), 256, 0, stream>>>(ctx, Wt + 3 * 1048576, nullptr, nullptr, out, 1024);
}